// Round 6
// baseline (605.607 us; speedup 1.0000x reference)
//
#include <hip/hip_runtime.h>

// ---- DPP helpers (row = 16 lanes; our site-group is exactly one DPP row) ----
#define DPP_XOR1        0xB1   // lane ^= 1
#define DPP_XOR2        0x4E   // lane ^= 2
#define DPP_HALF_MIRROR 0x141  // lane ^= 7
#define DPP_ROW_MIRROR  0x140  // lane ^= 15

template <int CTRL>
__device__ __forceinline__ float dppf(float x) {
    int i = __builtin_bit_cast(int, x);
    int o = __builtin_amdgcn_update_dpp(0, i, CTRL, 0xF, 0xF, true);
    return __builtin_bit_cast(float, o);
}

__device__ __forceinline__ float allsum16(float v) {
    v += dppf<DPP_XOR1>(v);
    v += dppf<DPP_XOR2>(v);
    v += dppf<DPP_HALF_MIRROR>(v);
    v += dppf<DPP_ROW_MIRROR>(v);
    return v;
}

// One site (b,o,h,w) per 16 lanes; 16 sites per 256-thread block.
// Stage 16 KB/block through LDS with fully-coalesced global loads
// (1 KB contiguous per wave instruction) + XOR-swizzled LDS layout
// (conflict-free on both ds_write_b128 and ds_read_b128 — verified by
//  enumeration: 8 lanes per bank-quad on every access).
__global__ __launch_bounds__(256, 4)
void caps_route_kernel(const float* __restrict__ pred,
                       const float* __restrict__ bias,
                       const int* __restrict__ nitp,
                       float* __restrict__ out,
                       int bsites) {
    __shared__ float4 lds[1024];            // 16 sites x 64 float4 = 16 KB

    const int tid   = threadIdx.x;
    const int l     = tid & 63;             // lane in wave
    const int wv    = tid >> 6;             // wave in block (0..3)
    const int r     = tid & 15;             // row owned by this thread
    const int sb    = tid >> 4;             // site-in-block (0..15)
    const int bsite = (blockIdx.x << 4) + sb;
    const size_t siteBlk = (size_t)blockIdx.y * bsites + ((size_t)blockIdx.x << 4);
    const int nit = nitp[0];

    // ---- coalesced stage: global -> regs -> LDS (swizzled) ----
    // Wave wv stages sites [4wv, 4wv+4); load k gives lane l float4 #l of
    // site 4wv+k (contiguous 1 KB per instruction). Swizzle: p4 = a4 ^ (row&7).
    {
        const float4* gp = reinterpret_cast<const float4*>(pred)
                         + ((siteBlk + (wv << 2)) << 6) + l;
        const int wbase = (wv << 8) | (l ^ ((l >> 2) & 7));
        float4 v0 = gp[0];
        float4 v1 = gp[64];
        float4 v2 = gp[128];
        float4 v3 = gp[192];
        lds[wbase      ] = v0;
        lds[wbase + 64 ] = v1;
        lds[wbase + 128] = v2;
        lds[wbase + 192] = v3;
    }
    __syncthreads();

    // ---- LDS -> registers: P[r][0..15] for this thread's row ----
    float P[16];
    {
        const int rb = sb << 6;
        #pragma unroll
        for (int k = 0; k < 4; ++k) {
            float4 q = lds[rb + (((r << 2) | k) ^ (r & 7))];
            P[4 * k + 0] = q.x;
            P[4 * k + 1] = q.y;
            P[4 * k + 2] = q.z;
            P[4 * k + 3] = q.w;
        }
    }

    float bi = bias[((size_t)bsite << 4) + r];   // b[0,o,h,w,r]

    const bool h8 = (r & 8) != 0;
    const bool h4 = (r & 4) != 0;
    const bool h2 = (r & 2) != 0;
    const bool h1 = (r & 1) != 0;

    float o_val = 0.0f;

    // softmax(b) over 16 lanes -> weighted sum (DPP reduce-scatter) -> squash.
    // No max-subtraction: |b| <= nit * max|<P_i,out>| ~ 12, exp() safe in fp32.
    auto route_out = [&]() {
        float e = __expf(bi);
        float S = allsum16(e);

        float t[16];
        #pragma unroll
        for (int d = 0; d < 16; ++d) t[d] = e * P[d];

        // reduce-scatter: after each butterfly stage, select on the matching
        // lane-bit so lane r ends holding u[r] = sum_i e_i * P[i][r].
        #pragma unroll
        for (int d = 0; d < 16; ++d) t[d] += dppf<DPP_ROW_MIRROR>(t[d]);
        #pragma unroll
        for (int k = 0; k < 8; ++k) t[k] = h8 ? t[k + 8] : t[k];
        #pragma unroll
        for (int d = 0; d < 8; ++d) t[d] += dppf<DPP_HALF_MIRROR>(t[d]);
        #pragma unroll
        for (int k = 0; k < 4; ++k) t[k] = h4 ? t[k + 4] : t[k];
        #pragma unroll
        for (int d = 0; d < 4; ++d) t[d] += dppf<DPP_XOR2>(t[d]);
        #pragma unroll
        for (int k = 0; k < 2; ++k) t[k] = h2 ? t[k + 2] : t[k];
        #pragma unroll
        for (int d = 0; d < 2; ++d) t[d] += dppf<DPP_XOR1>(t[d]);
        float u = h1 ? t[1] : t[0];

        // squash on s = u/S, with 1/S folded into the final scale:
        // nsq = (sum u^2)/S^2 ; o = u * (1/S) * nsq/sqrt(nsq+eps)/(1+nsq)
        float rS  = __builtin_amdgcn_rcpf(S);
        float nsq = allsum16(u * u) * rS * rS;
        float k_s = rS * nsq * __builtin_amdgcn_rsqf(nsq + 1e-7f) *
                    __builtin_amdgcn_rcpf(1.0f + nsq);
        o_val = u * k_s;   // lane r holds out[r]
    };

    route_out();

    const int gbase = (tid & 48) << 2;   // 16-lane group base, byte addr for bpermute

    for (int it = 0; it < nit; ++it) {
        // allgather out[0..15] via ds_bpermute (DS pipe, overlaps VALU)
        const int ov = __builtin_bit_cast(int, o_val);
        float agr = 0.0f;
        #pragma unroll
        for (int j = 0; j < 16; ++j) {
            float Aj = __builtin_bit_cast(float,
                        __builtin_amdgcn_ds_bpermute(gbase + (j << 2), ov));
            agr = fmaf(P[j], Aj, agr);   // <P[r,:], out>
        }
        bi += agr;
        route_out();
    }

    // out[site*16 + r]; whole wave writes 256B contiguous
    out[((siteBlk + sb) << 4) + r] = o_val;
}

extern "C" void kernel_launch(void* const* d_in, const int* in_sizes, int n_in,
                              void* d_out, int out_size, void* d_ws, size_t ws_size,
                              hipStream_t stream) {
    const float* pred = (const float*)d_in[0];
    const float* bias = (const float*)d_in[1];
    const int*   nit  = (const int*)d_in[2];
    float* outp = (float*)d_out;

    const int bsites = in_sizes[1] >> 4;              // O*H*W  (bias sites)
    const int batch  = (int)(((size_t)in_sizes[0] >> 8) / (size_t)bsites);  // B

    dim3 block(256);                                   // 16 sites per block
    dim3 grid(bsites >> 4, batch);                     // bsites is a multiple of 16
    caps_route_kernel<<<grid, block, 0, stream>>>(pred, bias, nit, outp, bsites);
}

// Round 7
// 366.004 us; speedup vs baseline: 1.6546x; 1.6546x over previous
//
#include <hip/hip_runtime.h>

// ---- DPP helpers (row = 16 lanes; our site-group is exactly one DPP row) ----
#define DPP_XOR1        0xB1   // lane ^= 1
#define DPP_XOR2        0x4E   // lane ^= 2
#define DPP_HALF_MIRROR 0x141  // lane ^= 7
#define DPP_ROW_MIRROR  0x140  // lane ^= 15

template <int CTRL>
__device__ __forceinline__ float dppf(float x) {
    int i = __builtin_bit_cast(int, x);
    int o = __builtin_amdgcn_update_dpp(0, i, CTRL, 0xF, 0xF, true);
    return __builtin_bit_cast(float, o);
}

__device__ __forceinline__ float allsum16(float v) {
    v += dppf<DPP_XOR1>(v);
    v += dppf<DPP_XOR2>(v);
    v += dppf<DPP_HALF_MIRROR>(v);
    v += dppf<DPP_ROW_MIRROR>(v);
    return v;
}

// One site (b,o,h,w) per 16 lanes; 16 sites per 256-thread block.
// Coalesced global->LDS staging (1 KB contiguous per wave instruction),
// XOR-swizzled LDS (conflict-free b128 write & read), then ALL per-thread
// state in NAMED SCALARS — r6's rocprof showed the compiler demoted the
// float[16] arrays to scratch (VGPR_Count=28, 555 MB of writes/dispatch).
__global__ __launch_bounds__(256, 4)
void caps_route_kernel(const float* __restrict__ pred,
                       const float* __restrict__ bias,
                       const int* __restrict__ nitp,
                       float* __restrict__ out,
                       int bsites) {
    __shared__ float4 lds[1024];            // 16 sites x 64 float4 = 16 KB

    const int tid   = threadIdx.x;
    const int l     = tid & 63;             // lane in wave
    const int wv    = tid >> 6;             // wave in block (0..3)
    const int r     = tid & 15;             // row owned by this thread
    const int sb    = tid >> 4;             // site-in-block (0..15)
    const int bsite = (blockIdx.x << 4) + sb;
    const size_t siteBlk = (size_t)blockIdx.y * bsites + ((size_t)blockIdx.x << 4);
    const int nit = nitp[0];

    // ---- coalesced stage: global -> regs -> LDS (swizzled) ----
    {
        const float4* gp = reinterpret_cast<const float4*>(pred)
                         + ((siteBlk + (wv << 2)) << 6) + l;
        const int wbase = (wv << 8) | (l ^ ((l >> 2) & 7));
        float4 v0 = gp[0];
        float4 v1 = gp[64];
        float4 v2 = gp[128];
        float4 v3 = gp[192];
        lds[wbase      ] = v0;
        lds[wbase + 64 ] = v1;
        lds[wbase + 128] = v2;
        lds[wbase + 192] = v3;
    }
    __syncthreads();

    // ---- LDS -> named scalar registers: P0..P15 = P[r][0..15] ----
    float P0, P1, P2, P3, P4, P5, P6, P7,
          P8, P9, P10, P11, P12, P13, P14, P15;
    {
        const int rb = sb << 6;
        float4 qa = lds[rb + (((r << 2) | 0) ^ (r & 7))];
        float4 qb = lds[rb + (((r << 2) | 1) ^ (r & 7))];
        float4 qc = lds[rb + (((r << 2) | 2) ^ (r & 7))];
        float4 qd = lds[rb + (((r << 2) | 3) ^ (r & 7))];
        P0  = qa.x; P1  = qa.y; P2  = qa.z; P3  = qa.w;
        P4  = qb.x; P5  = qb.y; P6  = qb.z; P7  = qb.w;
        P8  = qc.x; P9  = qc.y; P10 = qc.z; P11 = qc.w;
        P12 = qd.x; P13 = qd.y; P14 = qd.z; P15 = qd.w;
    }

    float bi = bias[((size_t)bsite << 4) + r];   // b[0,o,h,w,r]

    const bool h8 = (r & 8) != 0;
    const bool h4 = (r & 4) != 0;
    const bool h2 = (r & 2) != 0;
    const bool h1 = (r & 1) != 0;

    float o_val = 0.0f;

    // softmax(b) -> weighted sum (DPP reduce-scatter, all named scalars) -> squash
    auto route_out = [&]() {
        float e = __expf(bi);          // no max-sub: |b| <~ 12, fp32-safe
        float S = allsum16(e);

        float t0  = e * P0,  t1  = e * P1,  t2  = e * P2,  t3  = e * P3;
        float t4  = e * P4,  t5  = e * P5,  t6  = e * P6,  t7  = e * P7;
        float t8  = e * P8,  t9  = e * P9,  t10 = e * P10, t11 = e * P11;
        float t12 = e * P12, t13 = e * P13, t14 = e * P14, t15 = e * P15;

        // stage 1: lane ^= 15, then select on bit3
        t0  += dppf<DPP_ROW_MIRROR>(t0);   t1  += dppf<DPP_ROW_MIRROR>(t1);
        t2  += dppf<DPP_ROW_MIRROR>(t2);   t3  += dppf<DPP_ROW_MIRROR>(t3);
        t4  += dppf<DPP_ROW_MIRROR>(t4);   t5  += dppf<DPP_ROW_MIRROR>(t5);
        t6  += dppf<DPP_ROW_MIRROR>(t6);   t7  += dppf<DPP_ROW_MIRROR>(t7);
        t8  += dppf<DPP_ROW_MIRROR>(t8);   t9  += dppf<DPP_ROW_MIRROR>(t9);
        t10 += dppf<DPP_ROW_MIRROR>(t10);  t11 += dppf<DPP_ROW_MIRROR>(t11);
        t12 += dppf<DPP_ROW_MIRROR>(t12);  t13 += dppf<DPP_ROW_MIRROR>(t13);
        t14 += dppf<DPP_ROW_MIRROR>(t14);  t15 += dppf<DPP_ROW_MIRROR>(t15);
        t0 = h8 ? t8  : t0;  t1 = h8 ? t9  : t1;
        t2 = h8 ? t10 : t2;  t3 = h8 ? t11 : t3;
        t4 = h8 ? t12 : t4;  t5 = h8 ? t13 : t5;
        t6 = h8 ? t14 : t6;  t7 = h8 ? t15 : t7;

        // stage 2: lane ^= 7, then select on bit2
        t0 += dppf<DPP_HALF_MIRROR>(t0);   t1 += dppf<DPP_HALF_MIRROR>(t1);
        t2 += dppf<DPP_HALF_MIRROR>(t2);   t3 += dppf<DPP_HALF_MIRROR>(t3);
        t4 += dppf<DPP_HALF_MIRROR>(t4);   t5 += dppf<DPP_HALF_MIRROR>(t5);
        t6 += dppf<DPP_HALF_MIRROR>(t6);   t7 += dppf<DPP_HALF_MIRROR>(t7);
        t0 = h4 ? t4 : t0;  t1 = h4 ? t5 : t1;
        t2 = h4 ? t6 : t2;  t3 = h4 ? t7 : t3;

        // stage 3: lane ^= 2, then select on bit1
        t0 += dppf<DPP_XOR2>(t0);  t1 += dppf<DPP_XOR2>(t1);
        t2 += dppf<DPP_XOR2>(t2);  t3 += dppf<DPP_XOR2>(t3);
        t0 = h2 ? t2 : t0;  t1 = h2 ? t3 : t1;

        // stage 4: lane ^= 1, then select on bit0
        t0 += dppf<DPP_XOR1>(t0);  t1 += dppf<DPP_XOR1>(t1);
        float u = h1 ? t1 : t0;    // u[r] = sum_i e_i * P[i][r]

        // squash on s = u/S with 1/S folded into the final scale
        float rS  = __builtin_amdgcn_rcpf(S);
        float nsq = allsum16(u * u) * rS * rS;
        float k_s = rS * nsq * __builtin_amdgcn_rsqf(nsq + 1e-7f) *
                    __builtin_amdgcn_rcpf(1.0f + nsq);
        o_val = u * k_s;           // lane r holds out[r]
    };

    route_out();

    const int gbase = (tid & 48) << 2;   // 16-lane group base, byte addr for bpermute

    for (int it = 0; it < nit; ++it) {
        // allgather out[0..15] via ds_bpermute; consume immediately (no array)
        const int ov = __builtin_bit_cast(int, o_val);
        float agr = 0.0f;
#define AG_STEP(J, PJ)                                                         \
        {                                                                      \
            float Aj = __builtin_bit_cast(float,                               \
                __builtin_amdgcn_ds_bpermute(gbase + (J << 2), ov));           \
            agr = fmaf(PJ, Aj, agr);                                           \
        }
        AG_STEP(0,  P0)  AG_STEP(1,  P1)  AG_STEP(2,  P2)  AG_STEP(3,  P3)
        AG_STEP(4,  P4)  AG_STEP(5,  P5)  AG_STEP(6,  P6)  AG_STEP(7,  P7)
        AG_STEP(8,  P8)  AG_STEP(9,  P9)  AG_STEP(10, P10) AG_STEP(11, P11)
        AG_STEP(12, P12) AG_STEP(13, P13) AG_STEP(14, P14) AG_STEP(15, P15)
#undef AG_STEP
        bi += agr;
        route_out();
    }

    // out[site*16 + r]; whole wave writes 256B contiguous
    out[((siteBlk + sb) << 4) + r] = o_val;
}

extern "C" void kernel_launch(void* const* d_in, const int* in_sizes, int n_in,
                              void* d_out, int out_size, void* d_ws, size_t ws_size,
                              hipStream_t stream) {
    const float* pred = (const float*)d_in[0];
    const float* bias = (const float*)d_in[1];
    const int*   nit  = (const int*)d_in[2];
    float* outp = (float*)d_out;

    const int bsites = in_sizes[1] >> 4;              // O*H*W  (bias sites)
    const int batch  = (int)(((size_t)in_sizes[0] >> 8) / (size_t)bsites);  // B

    dim3 block(256);                                   // 16 sites per block
    dim3 grid(bsites >> 4, batch);                     // bsites divisible by 16
    caps_route_kernel<<<grid, block, 0, stream>>>(pred, bias, nit, outp, bsites);
}